// Round 6
// baseline (7994.230 us; speedup 1.0000x reference)
//
#include <hip/hip_runtime.h>
#include <math.h>

#define HH 256
#define FIN 6
#define TT 4096
#define BB 32
#define TH 0.05f

typedef _Float16 h2 __attribute__((ext_vector_type(2)));
typedef int iv32 __attribute__((ext_vector_type(32)));   // 32 regs = 32 packed h2 = 64 halfs
struct H8 { h2 a, b, c, d; };   // 16 B = 8 halfs

__device__ __forceinline__ int packh2(float a, float b) {
    h2 v = { (_Float16)a, (_Float16)b };
    return __builtin_bit_cast(int, v);
}
__device__ __forceinline__ h2 toh2(int x) { return __builtin_bit_cast(h2, x); }
__device__ __forceinline__ float fdot2(h2 a, h2 b, float c) {
    return __builtin_amdgcn_fdot2(a, b, c, false);
}

__device__ __forceinline__ float hswish(float v) {
    float c = fminf(fmaxf(v + 3.0f, 0.0f), 6.0f);
    return v * c * (1.0f / 6.0f);
}
__device__ __forceinline__ float fexp2(float x) { return __builtin_amdgcn_exp2f(x); }
__device__ __forceinline__ float frcp(float x)  { return __builtin_amdgcn_rcpf(x); }
__device__ __forceinline__ float sigm(float x)  { return frcp(1.0f + fexp2(-1.44269504f * x)); }
__device__ __forceinline__ float tanhf_fast(float x) {
    float ax = fabsf(x);
    float e = fexp2(2.88539008f * ax);           // exp(2|x|)
    float t = 1.0f - 2.0f * frcp(e + 1.0f);      // tanh(|x|)
    return copysignf(t, x);
}

// Kernel 1: feats (B,T,6) into ws, conv skip path into d_out.
__global__ __launch_bounds__(256) void k_prep(
        const float* __restrict__ x, const float* __restrict__ Wc1,
        const float* __restrict__ Wc2, float* __restrict__ feats,
        float* __restrict__ out) {
    int idx = blockIdx.x * 256 + threadIdx.x;   // b*T + t
    if (idx >= BB * TT) return;
    int b = idx >> 12;
    int t = idx & (TT - 1);
    const float* xb = x + (size_t)b * TT * 2;
    float i0 = xb[t * 2 + 0], q0 = xb[t * 2 + 1];
    float ip = (t > 0) ? xb[(t - 1) * 2 + 0] : 0.0f;
    float qp = (t > 0) ? xb[(t - 1) * 2 + 1] : 0.0f;
    float amp2 = i0 * i0 + q0 * q0;
    float amp  = sqrtf(fmaxf(amp2, 1e-12f));
    float amp3 = amp * amp2;
    float* f = feats + (size_t)idx * 6;
    f[0] = i0; f[1] = q0; f[2] = amp; f[3] = amp3; f[4] = ip; f[5] = qp;

    float c1[3];
#pragma unroll
    for (int m = 0; m < 3; m++) {
        float acc = 0.0f;
#pragma unroll
        for (int k = 0; k < 3; k++) {
            int tt = t + (k - 1) * 16;
            if (tt >= 0 && tt < TT) {
                acc += Wc1[m * 6 + 0 * 3 + k] * xb[tt * 2 + 0];
                acc += Wc1[m * 6 + 1 * 3 + k] * xb[tt * 2 + 1];
            }
        }
        c1[m] = hswish(acc);
    }
#pragma unroll
    for (int o = 0; o < 2; o++) {
        float acc = Wc2[o * 3 + 0] * c1[0] + Wc2[o * 3 + 1] * c1[1] + Wc2[o * 3 + 2] * c1[2];
        out[(size_t)idx * 2 + o] = hswish(acc);
    }
}

__device__ __forceinline__ iv32 load_pack(const float* rowptr, int s) {
    iv32 v{};
    const float4* p = (const float4*)rowptr + s * 16;
#pragma unroll
    for (int c = 0; c < 16; c++) {
        float4 t = p[c];
        v[2 * c]     = packh2(t.x, t.y);
        v[2 * c + 1] = packh2(t.z, t.w);
    }
    return v;
}

// One 64-wide K-span: 8 H8 LDS chunks against one iv32 per gate.
#define SPAN(S, WR, WZ, WN)                                                     \
    _Pragma("unroll")                                                           \
    for (int c = 0; c < 8; c++) {                                               \
        H8 d = dp[(S) * 8 + c];                                                 \
        ar = fdot2(d.a, toh2(WR[4 * c + 0]), ar);                               \
        az = fdot2(d.a, toh2(WZ[4 * c + 0]), az);                               \
        an = fdot2(d.a, toh2(WN[4 * c + 0]), an);                               \
        ar = fdot2(d.b, toh2(WR[4 * c + 1]), ar);                               \
        az = fdot2(d.b, toh2(WZ[4 * c + 1]), az);                               \
        an = fdot2(d.b, toh2(WN[4 * c + 1]), an);                               \
        ar = fdot2(d.c, toh2(WR[4 * c + 2]), ar);                               \
        az = fdot2(d.c, toh2(WZ[4 * c + 2]), az);                               \
        an = fdot2(d.c, toh2(WN[4 * c + 2]), an);                               \
        ar = fdot2(d.d, toh2(WR[4 * c + 3]), ar);                               \
        az = fdot2(d.d, toh2(WZ[4 * c + 3]), az);                               \
        an = fdot2(d.d, toh2(WN[4 * c + 3]), an);                               \
    }

// Kernel 2: delta-GRU, one block (1 CU) per batch, 256 threads (4 waves,
// 1 wave/SIMD -> 256-VGPR budget, empirically honored in round 2).
// Thread tid owns gate rows {tid, 256+tid, 512+tid}, full K=256.
// r-gate weights: 4 x iv32 in VGPRs (128 regs).
// z,n-gate weights: 8 x iv32 PINNED TO AGPRs via "+a" inline-asm constraint
// (256 AGPRs); element extracts become v_accvgpr_read feeding v_dot2.
// Re-pinned each iteration so LICM cannot hoist the reads out of the loop.
__global__ __launch_bounds__(256, 1) void k_gru(
        const float* __restrict__ feats, const float* __restrict__ Wx,
        const float* __restrict__ Wh, const float* __restrict__ Wo,
        float* __restrict__ out) {
    __shared__ float s_out[TT * 2];                    // 32 KB output accumulator
    __shared__ __align__(16) _Float16 s_dhh[2][HH];    // 1 KB, double-buffered dh (fp16)
    __shared__ __align__(16) float s_dx[2][8];         // dx fp32, padded to 8
    __shared__ float s_feat[2][128 * FIN];             // 6 KB, double-buffered feat windows

    const int tid = threadIdx.x;
    const int b = blockIdx.x;
    const float* fb = feats + (size_t)b * TT * FIN;

    for (int i = tid; i < TT * 2; i += 256) s_out[i] = 0.0f;
#pragma unroll
    for (int k = 0; k < 3; k++) s_feat[0][tid + k * 256] = fb[tid + k * 256];

    // r-gate weights in VGPRs
    const float* rowr = Wh + (size_t)(0 * HH + tid) * HH;
    iv32 wr0 = load_pack(rowr, 0), wr1 = load_pack(rowr, 1),
         wr2 = load_pack(rowr, 2), wr3 = load_pack(rowr, 3);

    // z,n-gate weights pinned into AGPRs
    const float* rowz = Wh + (size_t)(1 * HH + tid) * HH;
    const float* rown = Wh + (size_t)(2 * HH + tid) * HH;
    iv32 wz0 = load_pack(rowz, 0), wz1 = load_pack(rowz, 1),
         wz2 = load_pack(rowz, 2), wz3 = load_pack(rowz, 3);
    iv32 wn0 = load_pack(rown, 0), wn1 = load_pack(rown, 1),
         wn2 = load_pack(rown, 2), wn3 = load_pack(rown, 3);
    asm volatile("" : "+a"(wz0));
    asm volatile("" : "+a"(wz1));
    asm volatile("" : "+a"(wz2));
    asm volatile("" : "+a"(wz3));
    asm volatile("" : "+a"(wn0));
    asm volatile("" : "+a"(wn1));
    asm volatile("" : "+a"(wn2));
    asm volatile("" : "+a"(wn3));

    float wxr[FIN], wxz[FIN], wxn[FIN];
#pragma unroll
    for (int f = 0; f < FIN; f++) {
        wxr[f] = Wx[(size_t)(0 * HH + tid) * FIN + f];
        wxz[f] = Wx[(size_t)(1 * HH + tid) * FIN + f];
        wxn[f] = Wx[(size_t)(2 * HH + tid) * FIN + f];
    }
    const float wo0 = Wo[tid], wo1 = Wo[HH + tid];

    float h = 0.0f, hp = 0.0f, dmr = 0.0f, dmz = 0.0f, dmn = 0.0f, dmnh = 0.0f;
    float xp = 0.0f, curf = 0.0f;
    if (tid < FIN) curf = fb[tid];

    __syncthreads();

#pragma unroll 1
    for (int t = 0; t < TT; t++) {
        const int tb = t & 1;

        // re-pin AGPR residency (defeats LICM hoisting of the 256 reads)
        asm volatile("" : "+a"(wz0));
        asm volatile("" : "+a"(wz1));
        asm volatile("" : "+a"(wz2));
        asm volatile("" : "+a"(wz3));
        asm volatile("" : "+a"(wn0));
        asm volatile("" : "+a"(wn1));
        asm volatile("" : "+a"(wn2));
        asm volatile("" : "+a"(wn3));

        // stage NEXT feats window mid-way through the current one (WAR-safe)
        if ((t & 127) == 64 && t + 64 < TT) {
            const int w = (t >> 7) + 1;
#pragma unroll
            for (int k = 0; k < 3; k++)
                s_feat[w & 1][tid + k * 256] = fb[(size_t)w * 128 * FIN + tid + k * 256];
        }

        // ---- phase A: thresholded deltas ----
        {
            float dh = h - hp;
            bool keep = fabsf(dh) >= TH;
            s_dhh[tb][tid] = (_Float16)(keep ? dh : 0.0f);
            if (keep) hp = h;
        }
        if (tid < FIN) {
            float dx = curf - xp;
            bool keep = fabsf(dx) >= TH;
            s_dx[tb][tid] = keep ? dx : 0.0f;
            if (keep) xp = curf;
        }
        __syncthreads();

        // ---- phase B: mac_x (fp32) + full-K fp16 dots ----
        float mxr = dmr, mxz = dmz, mxn = dmn;
        {
            const float4* dx4 = (const float4*)s_dx[tb];
            float4 da = dx4[0], db = dx4[1];
            mxr = fmaf(da.x, wxr[0], mxr); mxz = fmaf(da.x, wxz[0], mxz); mxn = fmaf(da.x, wxn[0], mxn);
            mxr = fmaf(da.y, wxr[1], mxr); mxz = fmaf(da.y, wxz[1], mxz); mxn = fmaf(da.y, wxn[1], mxn);
            mxr = fmaf(da.z, wxr[2], mxr); mxz = fmaf(da.z, wxz[2], mxz); mxn = fmaf(da.z, wxn[2], mxn);
            mxr = fmaf(da.w, wxr[3], mxr); mxz = fmaf(da.w, wxz[3], mxz); mxn = fmaf(da.w, wxn[3], mxn);
            mxr = fmaf(db.x, wxr[4], mxr); mxz = fmaf(db.x, wxz[4], mxz); mxn = fmaf(db.x, wxn[4], mxn);
            mxr = fmaf(db.y, wxr[5], mxr); mxz = fmaf(db.y, wxz[5], mxz); mxn = fmaf(db.y, wxn[5], mxn);
        }
        float ar = 0.0f, az = 0.0f, an = 0.0f;
        const H8* dp = (const H8*)s_dhh[tb];
        SPAN(0, wr0, wz0, wn0)
        SPAN(1, wr1, wz1, wn1)
        SPAN(2, wr2, wz2, wn2)
        SPAN(3, wr3, wz3, wn3)

        dmr = mxr + ar;
        dmz = mxz + az;
        dmn = mxn;
        dmnh += an;

        // ---- phase C: gates + h update (thread-local) ----
        {
            float r = sigm(dmr);
            float z = sigm(dmz);
            float nn = tanhf_fast(dmn + r * dmnh);
            h = (1.0f - z) * nn + z * h;
        }

        // ---- output: h @ Wo.T, wave shfl-reduce + LDS atomic accumulate ----
        {
            float p0 = h * wo0, p1 = h * wo1;
#pragma unroll
            for (int s = 32; s >= 1; s >>= 1) {
                p0 += __shfl_down(p0, s, 64);
                p1 += __shfl_down(p1, s, 64);
            }
            if ((tid & 63) == 0) {
                atomicAdd(&s_out[2 * t + 0], p0);
                atomicAdd(&s_out[2 * t + 1], p1);
            }
        }

        // prefetch next step's feature from LDS window (no global access)
        if (tid < FIN && t + 1 < TT) {
            const int tn = t + 1;
            curf = s_feat[(tn >> 7) & 1][(tn & 127) * FIN + tid];
        }
    }

    __syncthreads();
    const size_t outbase = (size_t)b * TT * 2;
    for (int i = tid; i < TT * 2; i += 256) out[outbase + i] += s_out[i];
}

extern "C" void kernel_launch(void* const* d_in, const int* in_sizes, int n_in,
                              void* d_out, int out_size, void* d_ws, size_t ws_size,
                              hipStream_t stream) {
    const float* x   = (const float*)d_in[0];
    const float* Wx  = (const float*)d_in[1];
    const float* Wh  = (const float*)d_in[2];
    const float* Wo  = (const float*)d_in[3];
    const float* Wc1 = (const float*)d_in[4];
    const float* Wc2 = (const float*)d_in[5];
    float* out = (float*)d_out;
    float* feats = (float*)d_ws;              // B*T*6 fp32 = 3.1 MB

    k_prep<<<(BB * TT + 255) / 256, 256, 0, stream>>>(x, Wc1, Wc2, feats, out);
    k_gru<<<BB, 256, 0, stream>>>(feats, Wx, Wh, Wo, out);
}